// Round 1
// baseline (631.450 us; speedup 1.0000x reference)
//
#include <hip/hip_runtime.h>
#include <hip/hip_bf16.h>

typedef unsigned short u16;
typedef __attribute__((ext_vector_type(8))) __bf16 bf16x8;
typedef __attribute__((ext_vector_type(4))) float f32x4;

// ---------- helpers ----------
__device__ __forceinline__ u16 f2b(float f) {            // f32 -> bf16 RNE
  unsigned u = __builtin_bit_cast(unsigned, f);
  u = (u + 0x7fffu + ((u >> 16) & 1u)) >> 16;
  return (u16)u;
}

__device__ __forceinline__ f32x4 mfma_bf16(uint4 a, uint4 b, f32x4 c) {
  return __builtin_amdgcn_mfma_f32_16x16x32_bf16(
      __builtin_bit_cast(bf16x8, a), __builtin_bit_cast(bf16x8, b), c, 0, 0, 0);
}

__device__ __forceinline__ void gload_lds16(const u16* g, u16* l) {
  __builtin_amdgcn_global_load_lds(
      (const __attribute__((address_space(1))) unsigned int*)(g),
      (__attribute__((address_space(3))) unsigned int*)(l), 16, 0, 0);
}

__device__ __forceinline__ void cast8(const float* __restrict__ s, u16* __restrict__ d) {
  float4 a = *(const float4*)s;
  float4 b = *(const float4*)(s + 4);
  ushort4 lo, hi;
  lo.x = f2b(a.x); lo.y = f2b(a.y); lo.z = f2b(a.z); lo.w = f2b(a.w);
  hi.x = f2b(b.x); hi.y = f2b(b.y); hi.z = f2b(b.z); hi.w = f2b(b.w);
  *(ushort4*)d = lo;
  *(ushort4*)(d + 4) = hi;
}

// ---------- cast kernels ----------
__global__ __launch_bounds__(256) void cast_x(const float* __restrict__ src,
                                              u16* __restrict__ dst, int n) {
  int i = (blockIdx.x * 256 + threadIdx.x) * 8;
  if (i + 8 <= n) cast8(src + i, dst + i);
}

__global__ __launch_bounds__(256) void cast_w4(const float* __restrict__ w0,
                                               const float* __restrict__ w1,
                                               const float* __restrict__ w2,
                                               const float* __restrict__ w3,
                                               u16* __restrict__ dst) {
  const float* s = (blockIdx.y == 0) ? w0 : (blockIdx.y == 1) ? w1
                 : (blockIdx.y == 2) ? w2 : w3;
  u16* d = dst + (size_t)blockIdx.y * (1u << 20);
  int i = (blockIdx.x * 256 + threadIdx.x) * 8;
  cast8(s + i, d + i);
}

// ---------- 128x128 bf16 GEMM, C[i,j] = dot(A_row_i, B_row_j) + bias[j] ----------
// MODE 0: bf16 out [M][N].  MODE 1: bf16 out transposed to [B][H][hd][S] (for V).
// MODE 2: f32 out [M][N].
template <int MODE>
__global__ __launch_bounds__(256) void gemm128(const u16* __restrict__ A,
                                               const u16* __restrict__ Bm,
                                               const float* __restrict__ bias,
                                               void* __restrict__ Cout,
                                               int M, int N, int K) {
  __shared__ u16 lA[128 * 32];
  __shared__ u16 lB[128 * 32];
  const int tid = threadIdx.x;
  const int lane = tid & 63;
  const int w = tid >> 6;
  const int wr = w >> 1, wc = w & 1;
  const int rowBase = blockIdx.y * 128, colBase = blockIdx.x * 128;
  const int lo = lane & 15, g = lane >> 4;

  f32x4 acc[4][4] = {};

  const int r0 = tid >> 2;          // staging: row within 64-row chunk
  const int c0 = (tid & 3) * 8;     // staging: k-offset (8 bf16 = 16B)
  const u16* gA = A + (size_t)(rowBase + r0) * K + c0;
  const u16* gB = Bm + (size_t)(colBase + r0) * K + c0;
  u16* lAd = lA + w * 512;          // wave-uniform LDS dest (linear, G21)
  u16* lBd = lB + w * 512;

#pragma unroll 1
  for (int k0 = 0; k0 < K; k0 += 32) {
    gload_lds16(gA + k0, lAd);
    gload_lds16(gA + k0 + 64 * K, lAd + 2048);
    gload_lds16(gB + k0, lBd);
    gload_lds16(gB + k0 + 64 * K, lBd + 2048);
    __syncthreads();   // drains vmcnt -> LDS tiles ready
    uint4 af[4], bf[4];
#pragma unroll
    for (int m = 0; m < 4; ++m)
      af[m] = *(const uint4*)&lA[(wr * 64 + m * 16 + lo) * 32 + g * 8];
#pragma unroll
    for (int n = 0; n < 4; ++n)
      bf[n] = *(const uint4*)&lB[(wc * 64 + n * 16 + lo) * 32 + g * 8];
#pragma unroll
    for (int m = 0; m < 4; ++m)
#pragma unroll
      for (int n = 0; n < 4; ++n)
        acc[m][n] = mfma_bf16(af[m], bf[n], acc[m][n]);
    __syncthreads();   // all reads done before next-stage overwrite
  }

  const int cr = g * 4;   // C-layout: row = (lane>>4)*4 + reg, col = lane&15
  if constexpr (MODE == 1) {
    // V transposed store: token i -> (b, s), feature j -> (h, d); Vt[b][h][d][s]
#pragma unroll
    for (int m = 0; m < 4; ++m)
#pragma unroll
      for (int n = 0; n < 4; ++n) {
        int i0 = rowBase + wr * 64 + m * 16 + cr;
        int jf = colBase + wc * 64 + n * 16 + lo;
        float bv = bias[jf];
        int bb = i0 >> 11, s0 = i0 & 2047;
        int hh = jf >> 6, dd = jf & 63;
        ushort4 pk;
        pk.x = f2b(acc[m][n][0] + bv);
        pk.y = f2b(acc[m][n][1] + bv);
        pk.z = f2b(acc[m][n][2] + bv);
        pk.w = f2b(acc[m][n][3] + bv);
        *(ushort4*)((u16*)Cout + ((size_t)((bb * 16 + hh) * 64 + dd)) * 2048 + s0) = pk;
      }
  } else {
#pragma unroll
    for (int m = 0; m < 4; ++m)
#pragma unroll
      for (int n = 0; n < 4; ++n) {
        int gr = rowBase + wr * 64 + m * 16 + cr;
        int gc = colBase + wc * 64 + n * 16 + lo;
        float bv = bias[gc];
#pragma unroll
        for (int j = 0; j < 4; ++j) {
          float v = acc[m][n][j] + bv;
          if constexpr (MODE == 0)
            ((u16*)Cout)[(size_t)(gr + j) * N + gc] = f2b(v);
          else
            ((float*)Cout)[(size_t)(gr + j) * N + gc] = v;
        }
      }
  }
}

// ---------- flash attention with ALiBi ----------
// 4 independent waves/block (no barriers). Wave owns 32 q-rows.
// K fragments + V^T fragments read directly from global (L1/L2-resident per (b,h)).
// P goes C-layout -> A-fragment layout through padded per-wave LDS ([32][72], 2-way).
__global__ __launch_bounds__(256) void attn_fa(const u16* __restrict__ Qb,
                                               const u16* __restrict__ Kb,
                                               const u16* __restrict__ Vt,
                                               const int* __restrict__ mask,
                                               u16* __restrict__ Ob) {
  constexpr int S = 2048, D = 1024, H = 16;
  __shared__ u16 lP[4][32][72];
  const int tid = threadIdx.x, lane = tid & 63, w = tid >> 6;
  const int lo = lane & 15, g = lane >> 4;
  const int b = blockIdx.z, h = blockIdx.y;
  const int qt = blockIdx.x * 128 + w * 32;
  const float slope = exp2f(-(float)h * (1.0f / 16.0f));

  // Q fragments in registers (held across the whole K loop)
  uint4 aq[2][2];
#pragma unroll
  for (int m = 0; m < 2; ++m) {
    const u16* qp = Qb + (size_t)(b * S + qt + m * 16 + lo) * D + h * 64 + g * 8;
    aq[m][0] = *(const uint4*)qp;
    aq[m][1] = *(const uint4*)(qp + 32);
  }

  float mrow[2][4], lrow[2][4], qbias[2][4];
  f32x4 o[2][4] = {};
#pragma unroll
  for (int m = 0; m < 2; ++m)
#pragma unroll
    for (int j = 0; j < 4; ++j) {
      mrow[m][j] = -3.0e38f;
      lrow[m][j] = 0.0f;
      qbias[m][j] = slope * (float)(qt + m * 16 + g * 4 + j);
    }

  const u16* kbase = Kb + (size_t)b * S * D + h * 64;
  const u16* vbase = Vt + (size_t)(b * H + h) * 64 * S;

#pragma unroll 1
  for (int kt = 0; kt < S; kt += 64) {
    // ---- QK^T: scores[2 m][4 n] of 16x16, keys kt..kt+64 ----
    f32x4 sc[2][4] = {};
#pragma unroll
    for (int n = 0; n < 4; ++n) {
      const u16* kr = kbase + (size_t)(kt + n * 16 + lo) * D + g * 8;
      uint4 k0 = *(const uint4*)kr;
      uint4 k1 = *(const uint4*)(kr + 32);
#pragma unroll
      for (int m = 0; m < 2; ++m) {
        sc[m][n] = mfma_bf16(aq[m][0], k0, sc[m][n]);
        sc[m][n] = mfma_bf16(aq[m][1], k1, sc[m][n]);
      }
    }
    // ---- scale + ALiBi + mask ----
    float vals[2][4][4];
#pragma unroll
    for (int n = 0; n < 4; ++n) {
      int kg = kt + n * 16 + lo;
      float kb = slope * (float)kg;
      bool valid = mask[b * S + kg] != 0;
#pragma unroll
      for (int m = 0; m < 2; ++m)
#pragma unroll
        for (int j = 0; j < 4; ++j)
          vals[m][n][j] = valid ? sc[m][n][j] * 0.125f + kb - qbias[m][j]
                                : -__builtin_inff();
    }
    // ---- online softmax (row = g*4+j within 16-row frag; reduce over 16 lanes) ----
#pragma unroll
    for (int m = 0; m < 2; ++m)
#pragma unroll
      for (int j = 0; j < 4; ++j) {
        float pm = fmaxf(fmaxf(vals[m][0][j], vals[m][1][j]),
                         fmaxf(vals[m][2][j], vals[m][3][j]));
#pragma unroll
        for (int off = 1; off < 16; off <<= 1)
          pm = fmaxf(pm, __shfl_xor(pm, off));
        float mn = fmaxf(mrow[m][j], pm);
        float rs = __expf(mrow[m][j] - mn);
        mrow[m][j] = mn;
        float rsum = 0.f;
#pragma unroll
        for (int n = 0; n < 4; ++n) {
          float p = __expf(vals[m][n][j] - mn);
          vals[m][n][j] = p;
          rsum += p;
        }
#pragma unroll
        for (int off = 1; off < 16; off <<= 1)
          rsum += __shfl_xor(rsum, off);
        lrow[m][j] = lrow[m][j] * rs + rsum;
#pragma unroll
        for (int dn = 0; dn < 4; ++dn) o[m][dn][j] *= rs;
      }
    // ---- P: C-layout -> LDS -> A-fragment layout ----
#pragma unroll
    for (int m = 0; m < 2; ++m)
#pragma unroll
      for (int n = 0; n < 4; ++n)
#pragma unroll
        for (int j = 0; j < 4; ++j)
          lP[w][m * 16 + g * 4 + j][n * 16 + lo] = f2b(vals[m][n][j]);
    // (same-wave ds_write -> ds_read: compiler inserts lgkmcnt wait)
    // ---- PV: O += P @ V ----
#pragma unroll
    for (int kk = 0; kk < 2; ++kk) {
      uint4 pf0 = *(const uint4*)&lP[w][lo][kk * 32 + g * 8];
      uint4 pf1 = *(const uint4*)&lP[w][16 + lo][kk * 32 + g * 8];
#pragma unroll
      for (int dn = 0; dn < 4; ++dn) {
        const u16* vr = vbase + (size_t)(dn * 16 + lo) * S + kt + kk * 32 + g * 8;
        uint4 vf = *(const uint4*)vr;
        o[0][dn] = mfma_bf16(pf0, vf, o[0][dn]);
        o[1][dn] = mfma_bf16(pf1, vf, o[1][dn]);
      }
    }
  }
  // ---- normalize + store bf16 [B,S,H,hd] ----
#pragma unroll
  for (int m = 0; m < 2; ++m) {
    float inv[4];
#pragma unroll
    for (int j = 0; j < 4; ++j) inv[j] = 1.0f / fmaxf(lrow[m][j], 1e-30f);
#pragma unroll
    for (int dn = 0; dn < 4; ++dn) {
      int col = h * 64 + dn * 16 + lo;
#pragma unroll
      for (int j = 0; j < 4; ++j) {
        int q = qt + m * 16 + g * 4 + j;
        Ob[(size_t)(b * S + q) * D + col] = f2b(o[m][dn][j] * inv[j]);
      }
    }
  }
}

// ---------- host launcher ----------
extern "C" void kernel_launch(void* const* d_in, const int* in_sizes, int n_in,
                              void* d_out, int out_size, void* d_ws, size_t ws_size,
                              hipStream_t stream) {
  (void)in_sizes; (void)n_in; (void)out_size; (void)ws_size;
  const float* x  = (const float*)d_in[0];
  const float* Wq = (const float*)d_in[1];
  const float* bq = (const float*)d_in[2];
  const float* Wk = (const float*)d_in[3];
  const float* bk = (const float*)d_in[4];
  const float* Wv = (const float*)d_in[5];
  const float* bv = (const float*)d_in[6];
  const float* Wo = (const float*)d_in[7];
  const float* bo = (const float*)d_in[8];
  const int*  msk = (const int*)d_in[9];
  float* out = (float*)d_out;

  char* ws = (char*)d_ws;
  u16* xb  = (u16*)(ws);                    // 16MB; reused as attention output
  u16* Qb  = (u16*)(ws + ((size_t)16 << 20));
  u16* Kb  = (u16*)(ws + ((size_t)32 << 20));
  u16* Vt  = (u16*)(ws + ((size_t)48 << 20));
  u16* Wqb = (u16*)(ws + ((size_t)64 << 20));  // 4 weights, 2MB each, contiguous

  const int M = 8192, N = 1024, K = 1024;

  cast_x<<<4096, 256, 0, stream>>>(x, xb, M * K);
  cast_w4<<<dim3(512, 4), 256, 0, stream>>>(Wq, Wk, Wv, Wo, Wqb);

  gemm128<0><<<dim3(8, 64), 256, 0, stream>>>(xb, Wqb,               bq, Qb, M, N, K);
  gemm128<0><<<dim3(8, 64), 256, 0, stream>>>(xb, Wqb + (1u << 20),  bk, Kb, M, N, K);
  gemm128<1><<<dim3(8, 64), 256, 0, stream>>>(xb, Wqb + (2u << 20),  bv, Vt, M, N, K);

  attn_fa<<<dim3(16, 16, 4), 256, 0, stream>>>(Qb, Kb, Vt, msk, xb /*Ob reuses xb*/);

  gemm128<2><<<dim3(8, 64), 256, 0, stream>>>(xb, Wqb + (3u << 20),  bo, out, M, N, K);
}

// Round 3
// 484.392 us; speedup vs baseline: 1.3036x; 1.3036x over previous
//
#include <hip/hip_runtime.h>
#include <hip/hip_bf16.h>

typedef unsigned short u16;
typedef __attribute__((ext_vector_type(8))) __bf16 bf16x8;
typedef __attribute__((ext_vector_type(4))) float f32x4;

// ---------- helpers ----------
__device__ __forceinline__ u16 f2b(float f) {            // f32 -> bf16 RNE (manual)
  unsigned u = __builtin_bit_cast(unsigned, f);
  u = (u + 0x7fffu + ((u >> 16) & 1u)) >> 16;
  return (u16)u;
}

__device__ __forceinline__ u16 f2b_fast(float f) {       // native: enables v_cvt_pk_bf16_f32
  return __builtin_bit_cast(u16, (__bf16)f);
}

__device__ __forceinline__ f32x4 mfma_bf16(uint4 a, uint4 b, f32x4 c) {
  return __builtin_amdgcn_mfma_f32_16x16x32_bf16(
      __builtin_bit_cast(bf16x8, a), __builtin_bit_cast(bf16x8, b), c, 0, 0, 0);
}

__device__ __forceinline__ void gload_lds16(const u16* g, u16* l) {
  __builtin_amdgcn_global_load_lds(
      (const __attribute__((address_space(1))) unsigned int*)(g),
      (__attribute__((address_space(3))) unsigned int*)(l), 16, 0, 0);
}

__device__ __forceinline__ void cast8(const float* __restrict__ s, u16* __restrict__ d) {
  float4 a = *(const float4*)s;
  float4 b = *(const float4*)(s + 4);
  ushort4 lo, hi;
  lo.x = f2b(a.x); lo.y = f2b(a.y); lo.z = f2b(a.z); lo.w = f2b(a.w);
  hi.x = f2b(b.x); hi.y = f2b(b.y); hi.z = f2b(b.z); hi.w = f2b(b.w);
  *(ushort4*)d = lo;
  *(ushort4*)(d + 4) = hi;
}

// ---------- cast kernels ----------
__global__ __launch_bounds__(256) void cast_x(const float* __restrict__ src,
                                              u16* __restrict__ dst, int n) {
  int i = (blockIdx.x * 256 + threadIdx.x) * 8;
  if (i + 8 <= n) cast8(src + i, dst + i);
}

__global__ __launch_bounds__(256) void cast_w4(const float* __restrict__ w0,
                                               const float* __restrict__ w1,
                                               const float* __restrict__ w2,
                                               const float* __restrict__ w3,
                                               u16* __restrict__ dst) {
  const float* s = (blockIdx.y == 0) ? w0 : (blockIdx.y == 1) ? w1
                 : (blockIdx.y == 2) ? w2 : w3;
  u16* d = dst + (size_t)blockIdx.y * (1u << 20);
  int i = (blockIdx.x * 256 + threadIdx.x) * 8;
  cast8(s + i, d + i);
}

// mask -> additive bias {0, -3e38}
__global__ __launch_bounds__(256) void mask_bias(const int* __restrict__ msk,
                                                 float* __restrict__ mb, int n) {
  int i = blockIdx.x * 256 + threadIdx.x;
  if (i < n) mb[i] = msk[i] ? 0.0f : -3.0e38f;
}

// ---------- 128x128 bf16 GEMM, C[i,j] = dot(A_row_i, B_row_j) + bias[j] ----------
// MODE 0: bf16 out [M][N].  MODE 1: bf16 out transposed to [B][H][hd][S] (for V).
// MODE 2: f32 out [M][N].
template <int MODE>
__global__ __launch_bounds__(256) void gemm128(const u16* __restrict__ A,
                                               const u16* __restrict__ Bm,
                                               const float* __restrict__ bias,
                                               void* __restrict__ Cout,
                                               int M, int N, int K) {
  __shared__ u16 lA[128 * 32];
  __shared__ u16 lB[128 * 32];
  const int tid = threadIdx.x;
  const int lane = tid & 63;
  const int w = tid >> 6;
  const int wr = w >> 1, wc = w & 1;
  const int rowBase = blockIdx.y * 128, colBase = blockIdx.x * 128;
  const int lo = lane & 15, g = lane >> 4;

  f32x4 acc[4][4] = {};

  const int r0 = tid >> 2;
  const int c0 = (tid & 3) * 8;
  const u16* gA = A + (size_t)(rowBase + r0) * K + c0;
  const u16* gB = Bm + (size_t)(colBase + r0) * K + c0;
  u16* lAd = lA + w * 512;
  u16* lBd = lB + w * 512;

#pragma unroll 1
  for (int k0 = 0; k0 < K; k0 += 32) {
    gload_lds16(gA + k0, lAd);
    gload_lds16(gA + k0 + 64 * K, lAd + 2048);
    gload_lds16(gB + k0, lBd);
    gload_lds16(gB + k0 + 64 * K, lBd + 2048);
    __syncthreads();
    uint4 af[4], bf[4];
#pragma unroll
    for (int m = 0; m < 4; ++m)
      af[m] = *(const uint4*)&lA[(wr * 64 + m * 16 + lo) * 32 + g * 8];
#pragma unroll
    for (int n = 0; n < 4; ++n)
      bf[n] = *(const uint4*)&lB[(wc * 64 + n * 16 + lo) * 32 + g * 8];
#pragma unroll
    for (int m = 0; m < 4; ++m)
#pragma unroll
      for (int n = 0; n < 4; ++n)
        acc[m][n] = mfma_bf16(af[m], bf[n], acc[m][n]);
    __syncthreads();
  }

  const int cr = g * 4;
  if constexpr (MODE == 1) {
#pragma unroll
    for (int m = 0; m < 4; ++m)
#pragma unroll
      for (int n = 0; n < 4; ++n) {
        int i0 = rowBase + wr * 64 + m * 16 + cr;
        int jf = colBase + wc * 64 + n * 16 + lo;
        float bv = bias[jf];
        int bb = i0 >> 11, s0 = i0 & 2047;
        int hh = jf >> 6, dd = jf & 63;
        ushort4 pk;
        pk.x = f2b(acc[m][n][0] + bv);
        pk.y = f2b(acc[m][n][1] + bv);
        pk.z = f2b(acc[m][n][2] + bv);
        pk.w = f2b(acc[m][n][3] + bv);
        *(ushort4*)((u16*)Cout + ((size_t)((bb * 16 + hh) * 64 + dd)) * 2048 + s0) = pk;
      }
  } else {
#pragma unroll
    for (int m = 0; m < 4; ++m)
#pragma unroll
      for (int n = 0; n < 4; ++n) {
        int gr = rowBase + wr * 64 + m * 16 + cr;
        int gc = colBase + wc * 64 + n * 16 + lo;
        float bv = bias[gc];
#pragma unroll
        for (int j = 0; j < 4; ++j) {
          float v = acc[m][n][j] + bv;
          if constexpr (MODE == 0)
            ((u16*)Cout)[(size_t)(gr + j) * N + gc] = f2b(v);
          else
            ((float*)Cout)[(size_t)(gr + j) * N + gc] = v;
        }
      }
  }
}

// ---------- flash attention with ALiBi ----------
// 4 independent waves/block. Wave owns 32 q-rows, KVBLK=128 keys/iter.
// Softmax in log2 domain; -slope*q dropped (softmax shift-invariance).
// Mask folded into precomputed additive float bias mb[].
__global__ __launch_bounds__(256) void attn_fa(const u16* __restrict__ Qb,
                                               const u16* __restrict__ Kb,
                                               const u16* __restrict__ Vt,
                                               const float* __restrict__ mb,
                                               u16* __restrict__ Ob) {
  constexpr int S = 2048, D = 1024, H = 16;
  __shared__ u16 lP[4][32][136];   // stride 272B = 17*16B -> uniform bank spread
  const int tid = threadIdx.x, lane = tid & 63, w = tid >> 6;
  const int lo = lane & 15, g = lane >> 4;
  const int b = blockIdx.z, h = blockIdx.y;
  const int qt = blockIdx.x * 128 + w * 32;
  const float LOG2E = 1.4426950408889634f;
  const float slope2 = exp2f(-(float)h / 16.0f) * LOG2E;  // slope * log2(e)
  const float c1 = 0.125f * LOG2E;                        // scale * log2(e)

  // Q fragments in registers
  uint4 aq[2][2];
#pragma unroll
  for (int m = 0; m < 2; ++m) {
    const u16* qp = Qb + (size_t)(b * S + qt + m * 16 + lo) * D + h * 64 + g * 8;
    aq[m][0] = *(const uint4*)qp;
    aq[m][1] = *(const uint4*)(qp + 32);
  }

  float mrow[2][4], lrow[2][4];
  f32x4 o[2][4] = {};
#pragma unroll
  for (int m = 0; m < 2; ++m)
#pragma unroll
    for (int j = 0; j < 4; ++j) { mrow[m][j] = -3.0e38f; lrow[m][j] = 0.0f; }

  const u16* kbase = Kb + (size_t)b * S * D + h * 64;
  const u16* vbase = Vt + (size_t)(b * H + h) * 64 * S;
  const float* mbb = mb + b * S;

#pragma unroll 1
  for (int kt = 0; kt < S; kt += 128) {
    // ---- K fragment loads (batched 16-wide for latency) ----
    uint4 kf[8][2];
#pragma unroll
    for (int n = 0; n < 8; ++n) {
      const u16* kr = kbase + (size_t)(kt + n * 16 + lo) * D + g * 8;
      kf[n][0] = *(const uint4*)kr;
      kf[n][1] = *(const uint4*)(kr + 32);
    }
    // ---- per-key bias: slope*log2e*k + maskbias ----
    float kb[8];
#pragma unroll
    for (int n = 0; n < 8; ++n) {
      int kg = kt + n * 16 + lo;
      kb[n] = fmaf(slope2, (float)kg, mbb[kg]);
    }
    // ---- QK^T ----
    f32x4 sc[2][8] = {};
    __builtin_amdgcn_s_setprio(1);
#pragma unroll
    for (int n = 0; n < 8; ++n)
#pragma unroll
      for (int m = 0; m < 2; ++m) {
        sc[m][n] = mfma_bf16(aq[m][0], kf[n][0], sc[m][n]);
        sc[m][n] = mfma_bf16(aq[m][1], kf[n][1], sc[m][n]);
      }
    __builtin_amdgcn_s_setprio(0);
    // ---- z = s*c1 + kb (log2 domain, q-term dropped) ----
#pragma unroll
    for (int m = 0; m < 2; ++m)
#pragma unroll
      for (int n = 0; n < 8; ++n)
#pragma unroll
        for (int j = 0; j < 4; ++j)
          sc[m][n][j] = fmaf(sc[m][n][j], c1, kb[n]);
    // ---- online softmax per row (row = g*4+j within 16-row frag) ----
#pragma unroll
    for (int m = 0; m < 2; ++m)
#pragma unroll
      for (int j = 0; j < 4; ++j) {
        float pm = sc[m][0][j];
#pragma unroll
        for (int n = 1; n < 8; ++n) pm = fmaxf(pm, sc[m][n][j]);
#pragma unroll
        for (int off = 1; off < 16; off <<= 1)
          pm = fmaxf(pm, __shfl_xor(pm, off));
        float mn = fmaxf(mrow[m][j], pm);
        float rs = exp2f(mrow[m][j] - mn);
        mrow[m][j] = mn;
        float rsum = 0.f;
#pragma unroll
        for (int n = 0; n < 8; ++n) {
          float p = exp2f(sc[m][n][j] - mn);
          sc[m][n][j] = p;
          rsum += p;
        }
#pragma unroll
        for (int off = 1; off < 16; off <<= 1)
          rsum += __shfl_xor(rsum, off);
        lrow[m][j] = lrow[m][j] * rs + rsum;
#pragma unroll
        for (int dn = 0; dn < 4; ++dn) o[m][dn][j] *= rs;
      }
    // ---- P: C-layout -> LDS (native bf16 cast -> cvt_pk) ----
#pragma unroll
    for (int m = 0; m < 2; ++m)
#pragma unroll
      for (int n = 0; n < 8; ++n)
#pragma unroll
        for (int j = 0; j < 4; ++j)
          lP[w][m * 16 + g * 4 + j][n * 16 + lo] = f2b_fast(sc[m][n][j]);
    // ---- PV: O += P @ V ----
    __builtin_amdgcn_s_setprio(1);
#pragma unroll
    for (int kk = 0; kk < 4; ++kk) {
      uint4 pf0 = *(const uint4*)&lP[w][lo][kk * 32 + g * 8];
      uint4 pf1 = *(const uint4*)&lP[w][16 + lo][kk * 32 + g * 8];
#pragma unroll
      for (int dn = 0; dn < 4; ++dn) {
        const u16* vr = vbase + (size_t)(dn * 16 + lo) * S + kt + kk * 32 + g * 8;
        uint4 vf = *(const uint4*)vr;
        o[0][dn] = mfma_bf16(pf0, vf, o[0][dn]);
        o[1][dn] = mfma_bf16(pf1, vf, o[1][dn]);
      }
    }
    __builtin_amdgcn_s_setprio(0);
  }
  // ---- normalize + store bf16 [B,S,H,hd] ----
#pragma unroll
  for (int m = 0; m < 2; ++m) {
    float inv[4];
#pragma unroll
    for (int j = 0; j < 4; ++j) inv[j] = 1.0f / fmaxf(lrow[m][j], 1e-30f);
#pragma unroll
    for (int dn = 0; dn < 4; ++dn) {
      int col = h * 64 + dn * 16 + lo;
#pragma unroll
      for (int j = 0; j < 4; ++j) {
        int q = qt + m * 16 + g * 4 + j;
        Ob[(size_t)(b * S + q) * D + col] = f2b_fast(o[m][dn][j] * inv[j]);
      }
    }
  }
}

// ---------- host launcher ----------
extern "C" void kernel_launch(void* const* d_in, const int* in_sizes, int n_in,
                              void* d_out, int out_size, void* d_ws, size_t ws_size,
                              hipStream_t stream) {
  (void)in_sizes; (void)n_in; (void)out_size; (void)ws_size;
  const float* x  = (const float*)d_in[0];
  const float* Wq = (const float*)d_in[1];
  const float* bq = (const float*)d_in[2];
  const float* Wk = (const float*)d_in[3];
  const float* bk = (const float*)d_in[4];
  const float* Wv = (const float*)d_in[5];
  const float* bv = (const float*)d_in[6];
  const float* Wo = (const float*)d_in[7];
  const float* bo = (const float*)d_in[8];
  const int*  msk = (const int*)d_in[9];
  float* out = (float*)d_out;

  char* ws = (char*)d_ws;
  u16* xb  = (u16*)(ws);                       // 16MB; reused as attention output
  u16* Qb  = (u16*)(ws + ((size_t)16 << 20));
  u16* Kb  = (u16*)(ws + ((size_t)32 << 20));
  u16* Vt  = (u16*)(ws + ((size_t)48 << 20));
  u16* Wqb = (u16*)(ws + ((size_t)64 << 20));  // 4 weights, 2MB each
  float* mbf = (float*)(ws + ((size_t)72 << 20));  // mask bias, 32KB

  const int M = 8192, N = 1024, K = 1024;

  cast_x<<<4096, 256, 0, stream>>>(x, xb, M * K);
  cast_w4<<<dim3(512, 4), 256, 0, stream>>>(Wq, Wk, Wv, Wo, Wqb);
  mask_bias<<<32, 256, 0, stream>>>(msk, mbf, 8192);

  gemm128<0><<<dim3(8, 64), 256, 0, stream>>>(xb, Wqb,               bq, Qb, M, N, K);
  gemm128<0><<<dim3(8, 64), 256, 0, stream>>>(xb, Wqb + (1u << 20),  bk, Kb, M, N, K);
  gemm128<1><<<dim3(8, 64), 256, 0, stream>>>(xb, Wqb + (2u << 20),  bv, Vt, M, N, K);

  attn_fa<<<dim3(16, 16, 4), 256, 0, stream>>>(Qb, Kb, Vt, mbf, xb /*Ob reuses xb*/);

  gemm128<2><<<dim3(8, 64), 256, 0, stream>>>(xb, Wqb + (3u << 20),  bo, out, M, N, K);
}